// Round 17
// baseline (622.161 us; speedup 1.0000x reference)
//
#include <hip/hip_runtime.h>

#define M_TOK 32768
#define DIN   512
#define DEMB  1024
#define KC    4096

#define IDX_OFF ((size_t)M_TOK * DIN)                 // 16777216 floats
#define Q_OFF   (IDX_OFF + M_TOK)                     // 16809984
#define AUX_OFF (Q_OFF + (size_t)M_TOK * DEMB)        // 50364416

typedef _Float16 f16x8 __attribute__((ext_vector_type(8)));
typedef _Float16 f16x4 __attribute__((ext_vector_type(4)));
typedef float f32x4 __attribute__((ext_vector_type(4)));

__device__ inline void gload16(const void* g, void* s) {
    __builtin_amdgcn_global_load_lds((const __attribute__((address_space(1))) void*)g,
                                     (__attribute__((address_space(3))) void*)s, 16, 0, 0);
}

__device__ inline unsigned umin2(unsigned a, unsigned b) { return a < b ? a : b; }
__device__ inline unsigned umax2(unsigned a, unsigned b) { return a > b ? a : b; }

// ---------------- block reduction (256 threads = 4 waves) ----------------
__device__ inline float block_reduce_sum_256(float v) {
#pragma unroll
    for (int off = 32; off > 0; off >>= 1) v += __shfl_down(v, off);
    __shared__ float smem[4];
    const int lane = threadIdx.x & 63;
    const int w = threadIdx.x >> 6;
    if (lane == 0) smem[w] = v;
    __syncthreads();
    return smem[0] + smem[1] + smem[2] + smem[3];
}

// ---- fused prep: cbf+cn2' | wok pack | cbp pack | wpk pack --------------
__global__ __launch_bounds__(256) void prep_all(const float* __restrict__ cb,
                                                const float* __restrict__ w_out,
                                                const float* __restrict__ w_in,
                                                _Float16* __restrict__ cbf,
                                                _Float16* __restrict__ wok,
                                                _Float16* __restrict__ wpk,
                                                _Float16* __restrict__ cbp,
                                                float* __restrict__ cn2p,
                                                float* __restrict__ aux) {
    const int b = blockIdx.x;
    if (b < 4096) {
        if (b == 0 && threadIdx.x == 0) *aux = 0.0f;
        const float4 v = reinterpret_cast<const float4*>(cb + (size_t)b * DEMB)[threadIdx.x];
        f16x4 h;
        h[0] = (_Float16)v.x; h[1] = (_Float16)v.y; h[2] = (_Float16)v.z; h[3] = (_Float16)v.w;
        reinterpret_cast<f16x4*>(cbf + (size_t)b * DEMB)[threadIdx.x] = h;
        float s = v.x * v.x + v.y * v.y + v.z * v.z + v.w * v.w;
        s = block_reduce_sum_256(s);
        if (threadIdx.x == 0) cn2p[b] = 0.5f * s + 1024.0f;
    } else if (b < 4352) {
        const int id = (b - 4096) * 256 + threadIdx.x;   // < 65536
        const int l = id & 63;
        const int c16 = (id >> 6) & 31;
        const int kk = id >> 11;                         // 0..31
        const int col = c16 * 16 + (l & 15);
        const int kb = kk * 32 + (l >> 4) * 8;
        const float* src = w_out + (size_t)col * DEMB + kb;
        const float4 a = *reinterpret_cast<const float4*>(src);
        const float4 b4 = *reinterpret_cast<const float4*>(src + 4);
        f16x8 h;
        h[0] = (_Float16)a.x; h[1] = (_Float16)a.y; h[2] = (_Float16)a.z; h[3] = (_Float16)a.w;
        h[4] = (_Float16)b4.x; h[5] = (_Float16)b4.y; h[6] = (_Float16)b4.z; h[7] = (_Float16)b4.w;
        *reinterpret_cast<f16x8*>(wok + (size_t)id * 8) = h;
    } else if (b < 6400) {
        const int id = (b - 4352) * 256 + threadIdx.x;   // < 524288
        const int c16 = id >> 11;                        // 0..255
        const int rem = id & 2047;
        const int kk = rem >> 6;                         // 0..31
        const int l = rem & 63;
        const int lgq = l >> 4, lcq = l & 15;
        const float* src = cb + ((size_t)(c16 * 16 + lcq)) * DEMB + kk * 32 + lgq * 8;
        const float4 a = *reinterpret_cast<const float4*>(src);
        const float4 b4 = *reinterpret_cast<const float4*>(src + 4);
        f16x8 h;
        h[0] = (_Float16)a.x; h[1] = (_Float16)a.y; h[2] = (_Float16)a.z; h[3] = (_Float16)a.w;
        h[4] = (_Float16)b4.x; h[5] = (_Float16)b4.y; h[6] = (_Float16)b4.z; h[7] = (_Float16)b4.w;
        const int ntile = c16 >> 2, nn = c16 & 3;
        const size_t off = ((size_t)(kk * 256 + ntile * 4 + nn)) * 64 + l;   // f16x8 units
        *reinterpret_cast<f16x8*>(cbp + off * 8) = h;
    } else {
        const int id = (b - 6400) * 256 + threadIdx.x;   // < 131072
        const int l = id & 63;
        const int hl = (id >> 6) & 1;                    // wave-uniform
        const int c16 = (id >> 7) & 63;
        const int kk = id >> 13;                         // 0..15
        const int col = c16 * 16 + (l & 15);
        const int kb = kk * 32 + (l >> 4) * 8;
        const float* src = w_in + (size_t)col * DIN + kb;
        const float4 a = *reinterpret_cast<const float4*>(src);
        const float4 b4 = *reinterpret_cast<const float4*>(src + 4);
        const float e[8] = {a.x, a.y, a.z, a.w, b4.x, b4.y, b4.z, b4.w};
        f16x8 o;
#pragma unroll
        for (int j = 0; j < 8; ++j) {
            const _Float16 hv = (_Float16)e[j];
            o[j] = hl ? (_Float16)((e[j] - (float)hv) * 2048.0f) : hv;
        }
        *reinterpret_cast<f16x8*>(wpk + (size_t)id * 8) = o;
    }
}

// ---------------- z = x @ w_in^T + b: barrier-free streaming split GEMM ---
__global__ void __launch_bounds__(512)
__attribute__((amdgpu_waves_per_eu(2, 2)))
zgemm_stream(const float* __restrict__ x,
             const _Float16* __restrict__ wpk,
             const float* __restrict__ bin,
             float* __restrict__ zq,
             _Float16* __restrict__ zf) {
    extern __shared__ _Float16 sm[];   // Ah [64][512] swizzled; Al at +32768
    _Float16* Ah = sm;
    _Float16* Al = sm + 32768;
    const int t = threadIdx.x;
    const int w = t >> 6, l = t & 63;
    const int lg = l >> 4, lc = l & 15;
    const int m0 = blockIdx.x * 64;

    {
        const int r = t >> 3;
        const int c0 = t & 7;
#pragma unroll
        for (int i = 0; i < 8; ++i) {
            const int c = c0 + i * 8;
            const float* px = x + (size_t)(m0 + r) * DIN + c * 8;
            const float4 a = *reinterpret_cast<const float4*>(px);
            const float4 b4 = *reinterpret_cast<const float4*>(px + 4);
            const float e[8] = {a.x, a.y, a.z, a.w, b4.x, b4.y, b4.z, b4.w};
            f16x8 h, lo;
#pragma unroll
            for (int j = 0; j < 8; ++j) {
                const _Float16 hv = (_Float16)e[j];
                h[j] = hv;
                lo[j] = (_Float16)((e[j] - (float)hv) * 2048.0f);
            }
            const int swz = (c & 0x30) | ((c ^ r) & 15);
            *reinterpret_cast<f16x8*>(Ah + (size_t)(r * 64 + swz) * 8) = h;
            *reinterpret_cast<f16x8*>(Al + (size_t)(r * 64 + swz) * 8) = lo;
        }
    }

    const char* ztb = (const char*)sm;
    int lbase[4][4];
#pragma unroll
    for (int m = 0; m < 4; ++m)
#pragma unroll
        for (int j = 0; j < 4; ++j)
            lbase[m][j] = (m * 16 + lc) * 1024 + ((((j * 4) | lg) ^ lc) & 15) * 16;

    const char* pL = (const char*)wpk + w * 4096 + l * 16;

    f16x8 bh[2][2], bl[2][2];
#pragma unroll
    for (int s = 0; s < 2; ++s)
#pragma unroll
        for (int n = 0; n < 2; ++n) {
            bh[s][n] = *reinterpret_cast<const f16x8*>(pL + s * 131072 + n * 2048);
            bl[s][n] = *reinterpret_cast<const f16x8*>(pL + s * 131072 + n * 2048 + 1024);
        }

    __syncthreads();   // the only barrier

    f16x8 ah[2][4], al[2][4];
#pragma unroll
    for (int m = 0; m < 4; ++m) {
        ah[0][m] = *reinterpret_cast<const f16x8*>(ztb + lbase[m][0]);
        al[0][m] = *reinterpret_cast<const f16x8*>(ztb + 65536 + lbase[m][0]);
    }

    unsigned boff = 2u * 131072u;
    for (int p = 0; p < 4; ++p) {
        f32x4 acc1[4][2], acc2[4][2];
#pragma unroll
        for (int n = 0; n < 2; ++n) {
            const float bb = bin[p * 256 + w * 32 + n * 16 + lc];
#pragma unroll
            for (int m = 0; m < 4; ++m) {
                acc1[m][n] = (f32x4){bb, bb, bb, bb};
                acc2[m][n] = (f32x4){0.f, 0.f, 0.f, 0.f};
            }
        }
        const unsigned wrapAdd = (unsigned)((p < 3 ? 1 : -3) * 32768 - 15 * 131072);
#pragma unroll
        for (int kk = 0; kk < 16; ++kk) {
            const int nk = (kk + 1) & 15;
#pragma unroll
            for (int m = 0; m < 4; ++m) {
                ah[(kk + 1) & 1][m] = *reinterpret_cast<const f16x8*>(
                    ztb + lbase[m][nk & 3] + ((nk >> 2) << 8));
                al[(kk + 1) & 1][m] = *reinterpret_cast<const f16x8*>(
                    ztb + 65536 + lbase[m][nk & 3] + ((nk >> 2) << 8));
            }
            __builtin_amdgcn_s_setprio(1);
#pragma unroll
            for (int m = 0; m < 4; ++m)
#pragma unroll
                for (int n = 0; n < 2; ++n) {
                    acc1[m][n] = __builtin_amdgcn_mfma_f32_16x16x32_f16(
                        ah[kk & 1][m], bh[kk & 1][n], acc1[m][n], 0, 0, 0);
                    acc2[m][n] = __builtin_amdgcn_mfma_f32_16x16x32_f16(
                        ah[kk & 1][m], bl[kk & 1][n], acc2[m][n], 0, 0, 0);
                    acc2[m][n] = __builtin_amdgcn_mfma_f32_16x16x32_f16(
                        al[kk & 1][m], bh[kk & 1][n], acc2[m][n], 0, 0, 0);
                }
            __builtin_amdgcn_s_setprio(0);
#pragma unroll
            for (int n = 0; n < 2; ++n) {
                bh[kk & 1][n] = *reinterpret_cast<const f16x8*>(pL + boff + n * 2048);
                bl[kk & 1][n] = *reinterpret_cast<const f16x8*>(pL + boff + n * 2048 + 1024);
            }
            boff += (kk == 13) ? wrapAdd : 131072u;
        }
#pragma unroll
        for (int n = 0; n < 2; ++n) {
            const int col = p * 256 + w * 32 + n * 16 + lc;
#pragma unroll
            for (int m = 0; m < 4; ++m)
#pragma unroll
                for (int rg = 0; rg < 4; ++rg) {
                    const int row = m0 + m * 16 + lg * 4 + rg;
                    const float z = acc1[m][n][rg] + acc2[m][n][rg] * (1.0f / 2048.0f);
                    zq[(size_t)row * DEMB + col] = z;
                    zf[(size_t)row * DEMB + col] = (_Float16)(-z);
                }
        }
    }
}

// ---- mega kernel (32-token blocks, 2 blocks/CU for phase overlap) -------
// Same validated phases as R16, M halved: 64 KB panel -> two blocks
// co-resident (16 waves/CU), so block A's memory-bound refine overlaps
// block B's MFMA sweep. bf rings depth-2 (distance-2 covers L2 latency);
// state trimmed to fit the 128-VGPR cap at 4 waves/SIMD.
__global__ void __launch_bounds__(512)
__attribute__((amdgpu_waves_per_eu(4, 4)))
dist_refine_out(const _Float16* __restrict__ zf,
                const _Float16* __restrict__ cbp,
                const float* __restrict__ cn2p,
                const float* __restrict__ cb,
                const _Float16* __restrict__ cbf,
                const _Float16* __restrict__ wok,
                const float* __restrict__ bout,
                float* __restrict__ zq,
                float* __restrict__ idx_f,
                float* __restrict__ out,
                float* __restrict__ aux) {
    extern __shared__ _Float16 zt[];   // [32][1024] panel; reused for keys, then cbf rows
    __shared__ int idxs[32];           // static: survives panel overwrite
    const int t = threadIdx.x;
    const int w = t >> 6, l = t & 63;
    const int lg = l >> 4, lc = l & 15;
    const int m0 = blockIdx.x * 32;

    // -- phase 1: stage -z panel (32 rows) --
    {
        const int r0 = t >> 7;          // 0..3
        const int ch = t & 127;
#pragma unroll
        for (int i = 0; i < 8; ++i) {
            const int row = i * 4 + r0;
            const int sch = (ch & 0x70) | ((ch ^ row) & 15);
            gload16(zf + (((size_t)(m0 + row)) << 10) + sch * 8,
                    zt + ((size_t)(i * 512 + t)) * 8);
        }
    }

    const char* ztb = (const char*)zt;
    int lbase[2][4];
#pragma unroll
    for (int m = 0; m < 2; ++m)
#pragma unroll
        for (int j = 0; j < 4; ++j)
            lbase[m][j] = (m * 16 + lc) * 2048 + ((((j * 4) | lg) ^ lc) << 4);

    unsigned k0[8], k1[8];
#pragma unroll
    for (int r = 0; r < 8; ++r) { k0[r] = 0xFFFFFFFFu; k1[r] = 0xFFFFFFFFu; }

    const char* pL = (const char*)cbp + l * 16;

    f16x8 bf[2][4];   // depth-2 ring: byte off = ko*262144 + tile*4096 (+n*1024)
#pragma unroll
    for (int s = 0; s < 2; ++s)
#pragma unroll
        for (int n = 0; n < 4; ++n)
            bf[s][n] = *reinterpret_cast<const f16x8*>(pL + s * 262144 + w * 4096 + n * 1024);
    __syncthreads();

    // -- phase 2: sweep (verbatim logic, M=2 fragments) --
    f16x8 af[4][2];
#pragma unroll
    for (int s = 0; s < 2; ++s)
#pragma unroll
        for (int m = 0; m < 2; ++m)
            af[s][m] = *reinterpret_cast<const f16x8*>(ztb + lbase[m][s] + ((s & 28) << 6));

    unsigned boff = (unsigned)(w * 4096 + 2 * 262144);   // first reload (ko=2, tile=w)
    for (int nt8 = 0; nt8 < 8; ++nt8) {
        const int ntile = nt8 * 8 + w;
        const unsigned wrapAdd = (unsigned)((nt8 < 7 ? 8 : -56) * 4096 - 31 * 262144);
        const int colb = ntile * 64;
        unsigned colw[4];
        float c2[4];
#pragma unroll
        for (int n = 0; n < 4; ++n) {
            colw[n] = (unsigned)(colb + n * 16 + lc);
            c2[n] = cn2p[colw[n]];
        }
        f32x4 acc[2][4];
#pragma unroll
        for (int m = 0; m < 2; ++m)
#pragma unroll
            for (int n = 0; n < 4; ++n)
                acc[m][n] = (f32x4){c2[n], c2[n], c2[n], c2[n]};

#pragma unroll
        for (int kk = 0; kk < 32; ++kk) {
            const int nk2 = (kk + 2) & 31;
#pragma unroll
            for (int m = 0; m < 2; ++m)
                af[(kk + 2) & 3][m] = *reinterpret_cast<const f16x8*>(
                    ztb + lbase[m][nk2 & 3] + ((nk2 & 28) << 6));
            __builtin_amdgcn_s_setprio(1);
#pragma unroll
            for (int m = 0; m < 2; ++m)
#pragma unroll
                for (int n = 0; n < 4; ++n)
                    acc[m][n] = __builtin_amdgcn_mfma_f32_16x16x32_f16(
                        af[kk & 3][m], bf[kk & 1][n], acc[m][n], 0, 0, 0);
            __builtin_amdgcn_s_setprio(0);
            // reload just-consumed depth-2 slot for kk+2
#pragma unroll
            for (int n = 0; n < 4; ++n)
                bf[kk & 1][n] = *reinterpret_cast<const f16x8*>(pL + boff + n * 1024);
            boff += (kk == 29) ? wrapAdd : 262144u;
        }

#pragma unroll
        for (int n = 0; n < 4; ++n) {
#pragma unroll
            for (int m = 0; m < 2; ++m)
#pragma unroll
                for (int rg = 0; rg < 4; ++rg) {
                    const unsigned key =
                        (__float_as_uint(acc[m][n][rg]) & 0xFFFFF000u) | colw[n];
                    const int r = m * 4 + rg;
                    const unsigned kmax = umax2(k0[r], key);
                    k0[r] = umin2(k0[r], key);
                    k1[r] = umin2(k1[r], kmax);
                }
        }
    }
#pragma unroll
    for (int off = 1; off < 16; off <<= 1) {
#pragma unroll
        for (int r = 0; r < 8; ++r) {
            const unsigned b0 = __shfl_xor(k0[r], off);
            const unsigned b1 = __shfl_xor(k1[r], off);
            const unsigned lo = umin2(k0[r], b0);
            const unsigned hi = umax2(k0[r], b0);
            k0[r] = lo;
            k1[r] = umin2(hi, umin2(k1[r], b1));
        }
    }

    // -- phase 3: key handoff + refine (4 tokens/wave) --
    __syncthreads();   // all waves done reading the z panel
    unsigned* pks = (unsigned*)zt;   // [16 slots][32 tokens]
    if (lc == 0) {
#pragma unroll
        for (int m = 0; m < 2; ++m)
#pragma unroll
            for (int rg = 0; rg < 4; ++rg) {
                const int r = m * 4 + rg;
                const int tloc = m * 16 + lg * 4 + rg;
                pks[(w * 2 + 0) * 32 + tloc] = k0[r];
                pks[(w * 2 + 1) * 32 + tloc] = k1[r];
            }
    }
    __syncthreads();

    float asum = 0.0f;
    for (int i = 0; i < 4; ++i) {
        const int tloc = w * 4 + i;
        const int tok = m0 + tloc;
        float4* zp = reinterpret_cast<float4*>(zq + ((size_t)tok << 10));
        float4 zr[4];
#pragma unroll
        for (int j = 0; j < 4; ++j) zr[j] = zp[l + j * 64];

        float zn = 0.0f;
#pragma unroll
        for (int j = 0; j < 4; ++j) {
            zn = fmaf(zr[j].x, zr[j].x, zn);
            zn = fmaf(zr[j].y, zr[j].y, zn);
            zn = fmaf(zr[j].z, zr[j].z, zn);
            zn = fmaf(zr[j].w, zr[j].w, zn);
        }
#pragma unroll
        for (int off = 1; off < 64; off <<= 1) zn += __shfl_xor(zn, off);

        unsigned v = 0xFFFFFFFFu;
        if (l < 16) v = pks[l * 32 + tloc];

        float bestd = 3.4e38f;
        int besti = 0x7fffffff;
#pragma unroll
        for (int s = 0; s < 4; ++s) {
            unsigned mv = v;
#pragma unroll
            for (int off = 1; off < 64; off <<= 1) mv = umin2(mv, __shfl_xor(mv, off));
            if (v == mv) v = 0xFFFFFFFFu;  // consume winner (keys distinct by col)
            const int mi = (int)(mv & 0xFFFu);
            const float4* cp = reinterpret_cast<const float4*>(cb + ((size_t)mi << 10));
            float s4 = 0.0f;
#pragma unroll
            for (int j = 0; j < 4; ++j) {
                const float4 c = cp[l + j * 64];
                s4 = fmaf(zr[j].x, c.x, s4);
                s4 = fmaf(zr[j].y, c.y, s4);
                s4 = fmaf(zr[j].z, c.z, s4);
                s4 = fmaf(zr[j].w, c.w, s4);
            }
#pragma unroll
            for (int off = 1; off < 64; off <<= 1) s4 += __shfl_xor(s4, off);
            const float d = cn2p[mi] - s4;   // shifted by +1024 (rank-invariant)
            if (d < bestd || (d == bestd && mi < besti)) { bestd = d; besti = mi; }
        }
        const float4* cpb = reinterpret_cast<const float4*>(cb + ((size_t)besti << 10));
#pragma unroll
        for (int j = 0; j < 4; ++j) zp[l + j * 64] = cpb[l + j * 64];

        if (l == 0) {
            idx_f[tok] = (float)besti;
            idxs[tloc] = besti;
            asum += 2.0f * bestd - 2048.0f + zn;
        }
    }
    if (l == 0) atomicAdd(aux, asum * (1.0f / 33554432.0f));

    // -- phase 4: re-stage panel with gathered cbf rows (32 rows) --
    __syncthreads();   // idxs written; all waves done with pks/zq reads
    {
        const int r0 = t >> 7;
        const int ch = t & 127;
#pragma unroll
        for (int i = 0; i < 8; ++i) {
            const int row = i * 4 + r0;
            const int gi = idxs[row];
            const int sch = (ch & 0x70) | ((ch ^ row) & 15);
            gload16(cbf + (((size_t)gi) << 10) + sch * 8,
                    zt + ((size_t)(i * 512 + t)) * 8);
        }
    }
    const char* pLo = (const char*)wok + l * 16;
    f16x8 bfo[2][4];   // depth-2 ring
#pragma unroll
    for (int s = 0; s < 2; ++s)
#pragma unroll
        for (int n = 0; n < 4; ++n)
            bfo[s][n] = *reinterpret_cast<const f16x8*>(pLo + s * 32768 + w * 4096 + n * 1024);
    __syncthreads();   // panel staged

    // -- phase 5: outgemm main loop (M=2 fragments; reuses lbase) --
    f16x8 afo[4][2];
#pragma unroll
    for (int s = 0; s < 2; ++s)
#pragma unroll
        for (int m = 0; m < 2; ++m)
            afo[s][m] = *reinterpret_cast<const f16x8*>(ztb + lbase[m][s] + ((s & 28) << 6));

    f32x4 acco[2][4];
#pragma unroll
    for (int n = 0; n < 4; ++n) {
        const float bb = bout[w * 64 + n * 16 + lc];
#pragma unroll
        for (int m = 0; m < 2; ++m)
            acco[m][n] = (f32x4){bb, bb, bb, bb};
    }

    unsigned bo = (unsigned)(w * 4096 + 2 * 32768);
#pragma unroll
    for (int kk = 0; kk < 32; ++kk) {
        const int nk2 = (kk + 2) & 31;
#pragma unroll
        for (int m = 0; m < 2; ++m)
            afo[(kk + 2) & 3][m] = *reinterpret_cast<const f16x8*>(
                ztb + lbase[m][nk2 & 3] + ((nk2 & 28) << 6));
        __builtin_amdgcn_s_setprio(1);
#pragma unroll
        for (int m = 0; m < 2; ++m)
#pragma unroll
            for (int n = 0; n < 4; ++n)
                acco[m][n] = __builtin_amdgcn_mfma_f32_16x16x32_f16(
                    afo[kk & 3][m], bfo[kk & 1][n], acco[m][n], 0, 0, 0);
        __builtin_amdgcn_s_setprio(0);
#pragma unroll
        for (int n = 0; n < 4; ++n)
            bfo[kk & 1][n] = *reinterpret_cast<const f16x8*>(pLo + bo + n * 1024);
        bo += (kk == 29) ? (unsigned)(-(31 * 32768)) : 32768u;
    }

#pragma unroll
    for (int n = 0; n < 4; ++n) {
        const int col = w * 64 + n * 16 + lc;
#pragma unroll
        for (int m = 0; m < 2; ++m)
#pragma unroll
            for (int rg = 0; rg < 4; ++rg) {
                const int row = m0 + m * 16 + lg * 4 + rg;
                out[(size_t)row * DIN + col] = acco[m][n][rg];
            }
    }
}

extern "C" void kernel_launch(void* const* d_in, const int* in_sizes, int n_in,
                              void* d_out, int out_size, void* d_ws, size_t ws_size,
                              hipStream_t stream) {
    const float* x = (const float*)d_in[0];
    const float* w_in = (const float*)d_in[1];
    const float* b_in = (const float*)d_in[2];
    const float* w_out = (const float*)d_in[3];
    const float* b_out = (const float*)d_in[4];
    const float* cb = (const float*)d_in[5];

    float* out = (float*)d_out;              // [32768, 512]
    float* idx_f = out + IDX_OFF;            // [32768] as float
    float* zq = out + Q_OFF;                 // [32768, 1024]: z, then quantized
    float* aux = out + AUX_OFF;              // scalar
    _Float16* zf = (_Float16*)d_out;         // fp16 -z, aliases out slab (64 MiB)

    char* ws = (char*)d_ws;
    float* cn2p = (float*)ws;                          // 16 KB (shifted norms)
    _Float16* cbf = (_Float16*)(ws + 4341760);         // 8 MB flat fp16 codebook
    _Float16* cbp = (_Float16*)(ws + 12730368);        // 8 MB kk-major packed
    _Float16* wpk = (_Float16*)(ws + 21118976);        // 2 MB w_in hi/lo packed
    _Float16* wok = (_Float16*)(ws + 23216128);        // 1 MB w_out packed

    // 1) fused prep: cbf+cn2' | wok | cbp | wpk (all independent ranges)
    prep_all<<<6912, 256, 0, stream>>>(cb, w_out, w_in, cbf, wok, wpk, cbp, cn2p, aux);
    // 2) z = x @ w_in^T + b_in (barrier-free streaming split GEMM)
    zgemm_stream<<<M_TOK / 64, 512, 131072, stream>>>(x, wpk, b_in, zq, zf);
    // 3) mega: distance sweep + exact refine + q gather + out-GEMM
    //    (32-token blocks, 64 KB LDS -> 2 blocks/CU phase overlap)
    dist_refine_out<<<M_TOK / 32, 512, 65536, stream>>>(
        zf, cbp, cn2p, cb, cbf, wok, b_out, zq, idx_f, out, aux);
}

// Round 18
// 489.290 us; speedup vs baseline: 1.2716x; 1.2716x over previous
//
#include <hip/hip_runtime.h>

#define M_TOK 32768
#define DIN   512
#define DEMB  1024
#define KC    4096

#define IDX_OFF ((size_t)M_TOK * DIN)                 // 16777216 floats
#define Q_OFF   (IDX_OFF + M_TOK)                     // 16809984
#define AUX_OFF (Q_OFF + (size_t)M_TOK * DEMB)        // 50364416

typedef _Float16 f16x8 __attribute__((ext_vector_type(8)));
typedef _Float16 f16x4 __attribute__((ext_vector_type(4)));
typedef float f32x4 __attribute__((ext_vector_type(4)));

__device__ inline void gload16(const void* g, void* s) {
    __builtin_amdgcn_global_load_lds((const __attribute__((address_space(1))) void*)g,
                                     (__attribute__((address_space(3))) void*)s, 16, 0, 0);
}

__device__ inline unsigned umin2(unsigned a, unsigned b) { return a < b ? a : b; }
__device__ inline unsigned umax2(unsigned a, unsigned b) { return a > b ? a : b; }

// ---------------- block reduction (256 threads = 4 waves) ----------------
__device__ inline float block_reduce_sum_256(float v) {
#pragma unroll
    for (int off = 32; off > 0; off >>= 1) v += __shfl_down(v, off);
    __shared__ float smem[4];
    const int lane = threadIdx.x & 63;
    const int w = threadIdx.x >> 6;
    if (lane == 0) smem[w] = v;
    __syncthreads();
    return smem[0] + smem[1] + smem[2] + smem[3];
}

// ---- fused prep: cbf+cn2' | wok pack | cbp pack | wpk pack --------------
__global__ __launch_bounds__(256) void prep_all(const float* __restrict__ cb,
                                                const float* __restrict__ w_out,
                                                const float* __restrict__ w_in,
                                                _Float16* __restrict__ cbf,
                                                _Float16* __restrict__ wok,
                                                _Float16* __restrict__ wpk,
                                                _Float16* __restrict__ cbp,
                                                float* __restrict__ cn2p,
                                                float* __restrict__ aux) {
    const int b = blockIdx.x;
    if (b < 4096) {
        if (b == 0 && threadIdx.x == 0) *aux = 0.0f;
        const float4 v = reinterpret_cast<const float4*>(cb + (size_t)b * DEMB)[threadIdx.x];
        f16x4 h;
        h[0] = (_Float16)v.x; h[1] = (_Float16)v.y; h[2] = (_Float16)v.z; h[3] = (_Float16)v.w;
        reinterpret_cast<f16x4*>(cbf + (size_t)b * DEMB)[threadIdx.x] = h;
        float s = v.x * v.x + v.y * v.y + v.z * v.z + v.w * v.w;
        s = block_reduce_sum_256(s);
        if (threadIdx.x == 0) cn2p[b] = 0.5f * s + 1024.0f;
    } else if (b < 4352) {
        const int id = (b - 4096) * 256 + threadIdx.x;   // < 65536
        const int l = id & 63;
        const int c16 = (id >> 6) & 31;
        const int kk = id >> 11;                         // 0..31
        const int col = c16 * 16 + (l & 15);
        const int kb = kk * 32 + (l >> 4) * 8;
        const float* src = w_out + (size_t)col * DEMB + kb;
        const float4 a = *reinterpret_cast<const float4*>(src);
        const float4 b4 = *reinterpret_cast<const float4*>(src + 4);
        f16x8 h;
        h[0] = (_Float16)a.x; h[1] = (_Float16)a.y; h[2] = (_Float16)a.z; h[3] = (_Float16)a.w;
        h[4] = (_Float16)b4.x; h[5] = (_Float16)b4.y; h[6] = (_Float16)b4.z; h[7] = (_Float16)b4.w;
        *reinterpret_cast<f16x8*>(wok + (size_t)id * 8) = h;
    } else if (b < 6400) {
        const int id = (b - 4352) * 256 + threadIdx.x;   // < 524288
        const int c16 = id >> 11;                        // 0..255
        const int rem = id & 2047;
        const int kk = rem >> 6;                         // 0..31
        const int l = rem & 63;
        const int lgq = l >> 4, lcq = l & 15;
        const float* src = cb + ((size_t)(c16 * 16 + lcq)) * DEMB + kk * 32 + lgq * 8;
        const float4 a = *reinterpret_cast<const float4*>(src);
        const float4 b4 = *reinterpret_cast<const float4*>(src + 4);
        f16x8 h;
        h[0] = (_Float16)a.x; h[1] = (_Float16)a.y; h[2] = (_Float16)a.z; h[3] = (_Float16)a.w;
        h[4] = (_Float16)b4.x; h[5] = (_Float16)b4.y; h[6] = (_Float16)b4.z; h[7] = (_Float16)b4.w;
        const int ntile = c16 >> 2, nn = c16 & 3;
        const size_t off = ((size_t)(kk * 256 + ntile * 4 + nn)) * 64 + l;   // f16x8 units
        *reinterpret_cast<f16x8*>(cbp + off * 8) = h;
    } else {
        const int id = (b - 6400) * 256 + threadIdx.x;   // < 131072
        const int l = id & 63;
        const int hl = (id >> 6) & 1;                    // wave-uniform
        const int c16 = (id >> 7) & 63;
        const int kk = id >> 13;                         // 0..15
        const int col = c16 * 16 + (l & 15);
        const int kb = kk * 32 + (l >> 4) * 8;
        const float* src = w_in + (size_t)col * DIN + kb;
        const float4 a = *reinterpret_cast<const float4*>(src);
        const float4 b4 = *reinterpret_cast<const float4*>(src + 4);
        const float e[8] = {a.x, a.y, a.z, a.w, b4.x, b4.y, b4.z, b4.w};
        f16x8 o;
#pragma unroll
        for (int j = 0; j < 8; ++j) {
            const _Float16 hv = (_Float16)e[j];
            o[j] = hl ? (_Float16)((e[j] - (float)hv) * 2048.0f) : hv;
        }
        *reinterpret_cast<f16x8*>(wpk + (size_t)id * 8) = o;
    }
}

// ---------------- z = x @ w_in^T + b: barrier-free streaming split GEMM ---
__global__ void __launch_bounds__(512)
__attribute__((amdgpu_waves_per_eu(2, 2)))
zgemm_stream(const float* __restrict__ x,
             const _Float16* __restrict__ wpk,
             const float* __restrict__ bin,
             float* __restrict__ zq,
             _Float16* __restrict__ zf) {
    extern __shared__ _Float16 sm[];   // Ah [64][512] swizzled; Al at +32768
    _Float16* Ah = sm;
    _Float16* Al = sm + 32768;
    const int t = threadIdx.x;
    const int w = t >> 6, l = t & 63;
    const int lg = l >> 4, lc = l & 15;
    const int m0 = blockIdx.x * 64;

    {
        const int r = t >> 3;
        const int c0 = t & 7;
#pragma unroll
        for (int i = 0; i < 8; ++i) {
            const int c = c0 + i * 8;
            const float* px = x + (size_t)(m0 + r) * DIN + c * 8;
            const float4 a = *reinterpret_cast<const float4*>(px);
            const float4 b4 = *reinterpret_cast<const float4*>(px + 4);
            const float e[8] = {a.x, a.y, a.z, a.w, b4.x, b4.y, b4.z, b4.w};
            f16x8 h, lo;
#pragma unroll
            for (int j = 0; j < 8; ++j) {
                const _Float16 hv = (_Float16)e[j];
                h[j] = hv;
                lo[j] = (_Float16)((e[j] - (float)hv) * 2048.0f);
            }
            const int swz = (c & 0x30) | ((c ^ r) & 15);
            *reinterpret_cast<f16x8*>(Ah + (size_t)(r * 64 + swz) * 8) = h;
            *reinterpret_cast<f16x8*>(Al + (size_t)(r * 64 + swz) * 8) = lo;
        }
    }

    const char* ztb = (const char*)sm;
    int lbase[4][4];
#pragma unroll
    for (int m = 0; m < 4; ++m)
#pragma unroll
        for (int j = 0; j < 4; ++j)
            lbase[m][j] = (m * 16 + lc) * 1024 + ((((j * 4) | lg) ^ lc) & 15) * 16;

    const char* pL = (const char*)wpk + w * 4096 + l * 16;

    f16x8 bh[2][2], bl[2][2];
#pragma unroll
    for (int s = 0; s < 2; ++s)
#pragma unroll
        for (int n = 0; n < 2; ++n) {
            bh[s][n] = *reinterpret_cast<const f16x8*>(pL + s * 131072 + n * 2048);
            bl[s][n] = *reinterpret_cast<const f16x8*>(pL + s * 131072 + n * 2048 + 1024);
        }

    __syncthreads();   // the only barrier

    f16x8 ah[2][4], al[2][4];
#pragma unroll
    for (int m = 0; m < 4; ++m) {
        ah[0][m] = *reinterpret_cast<const f16x8*>(ztb + lbase[m][0]);
        al[0][m] = *reinterpret_cast<const f16x8*>(ztb + 65536 + lbase[m][0]);
    }

    unsigned boff = 2u * 131072u;
    for (int p = 0; p < 4; ++p) {
        f32x4 acc1[4][2], acc2[4][2];
#pragma unroll
        for (int n = 0; n < 2; ++n) {
            const float bb = bin[p * 256 + w * 32 + n * 16 + lc];
#pragma unroll
            for (int m = 0; m < 4; ++m) {
                acc1[m][n] = (f32x4){bb, bb, bb, bb};
                acc2[m][n] = (f32x4){0.f, 0.f, 0.f, 0.f};
            }
        }
        const unsigned wrapAdd = (unsigned)((p < 3 ? 1 : -3) * 32768 - 15 * 131072);
#pragma unroll
        for (int kk = 0; kk < 16; ++kk) {
            const int nk = (kk + 1) & 15;
#pragma unroll
            for (int m = 0; m < 4; ++m) {
                ah[(kk + 1) & 1][m] = *reinterpret_cast<const f16x8*>(
                    ztb + lbase[m][nk & 3] + ((nk >> 2) << 8));
                al[(kk + 1) & 1][m] = *reinterpret_cast<const f16x8*>(
                    ztb + 65536 + lbase[m][nk & 3] + ((nk >> 2) << 8));
            }
            __builtin_amdgcn_s_setprio(1);
#pragma unroll
            for (int m = 0; m < 4; ++m)
#pragma unroll
                for (int n = 0; n < 2; ++n) {
                    acc1[m][n] = __builtin_amdgcn_mfma_f32_16x16x32_f16(
                        ah[kk & 1][m], bh[kk & 1][n], acc1[m][n], 0, 0, 0);
                    acc2[m][n] = __builtin_amdgcn_mfma_f32_16x16x32_f16(
                        ah[kk & 1][m], bl[kk & 1][n], acc2[m][n], 0, 0, 0);
                    acc2[m][n] = __builtin_amdgcn_mfma_f32_16x16x32_f16(
                        al[kk & 1][m], bh[kk & 1][n], acc2[m][n], 0, 0, 0);
                }
            __builtin_amdgcn_s_setprio(0);
#pragma unroll
            for (int n = 0; n < 2; ++n) {
                bh[kk & 1][n] = *reinterpret_cast<const f16x8*>(pL + boff + n * 2048);
                bl[kk & 1][n] = *reinterpret_cast<const f16x8*>(pL + boff + n * 2048 + 1024);
            }
            boff += (kk == 13) ? wrapAdd : 131072u;
        }
#pragma unroll
        for (int n = 0; n < 2; ++n) {
            const int col = p * 256 + w * 32 + n * 16 + lc;
#pragma unroll
            for (int m = 0; m < 4; ++m)
#pragma unroll
                for (int rg = 0; rg < 4; ++rg) {
                    const int row = m0 + m * 16 + lg * 4 + rg;
                    const float z = acc1[m][n][rg] + acc2[m][n][rg] * (1.0f / 2048.0f);
                    zq[(size_t)row * DEMB + col] = z;
                    zf[(size_t)row * DEMB + col] = (_Float16)(-z);
                }
        }
    }
}

// ---- mega kernel: distance sweep + exact refine + gather + out-GEMM ----
// (R16 configuration: 64-token blocks, 1 block/CU; phases serialize but all
// launch gaps and intermediate round-trips are fused away. Occupancy-overlap
// variants failed three times on register-allocator behavior — R5/R11/R17.)
__global__ void __launch_bounds__(512)
__attribute__((amdgpu_waves_per_eu(2, 2)))
dist_refine_out(const _Float16* __restrict__ zf,
                const _Float16* __restrict__ cbp,
                const float* __restrict__ cn2p,
                const float* __restrict__ cb,
                const _Float16* __restrict__ cbf,
                const _Float16* __restrict__ wok,
                const float* __restrict__ bout,
                float* __restrict__ zq,
                float* __restrict__ idx_f,
                float* __restrict__ out,
                float* __restrict__ aux) {
    extern __shared__ _Float16 zt[];   // [64][1024] panel; reused for keys, then cbf rows
    __shared__ int idxs[64];           // static: survives panel overwrite
    const int t = threadIdx.x;
    const int w = t >> 6, l = t & 63;
    const int lg = l >> 4, lc = l & 15;
    const int m0 = blockIdx.x * 64;

    // -- phase 1: stage -z panel --
    {
        const int r0 = t >> 7;
        const int ch = t & 127;
#pragma unroll
        for (int i = 0; i < 16; ++i) {
            const int row = i * 4 + r0;
            const int sch = (ch & 0x70) | ((ch ^ row) & 15);
            gload16(zf + (((size_t)(m0 + row)) << 10) + sch * 8,
                    zt + ((size_t)(i * 512 + t)) * 8);
        }
    }

    const char* ztb = (const char*)zt;
    int lbase[4][4];
#pragma unroll
    for (int m = 0; m < 4; ++m)
#pragma unroll
        for (int j = 0; j < 4; ++j)
            lbase[m][j] = (m * 16 + lc) * 2048 + ((((j * 4) | lg) ^ lc) << 4);

    unsigned k0[16], k1[16];
#pragma unroll
    for (int r = 0; r < 16; ++r) { k0[r] = 0xFFFFFFFFu; k1[r] = 0xFFFFFFFFu; }

    const char* pL = (const char*)cbp + l * 16;

    f16x8 bf[4][4];
    {
#pragma unroll
        for (int s = 0; s < 4; ++s)
#pragma unroll
            for (int n = 0; n < 4; ++n)
                bf[s][n] = *reinterpret_cast<const f16x8*>(pL + s * 262144 + w * 4096 + n * 1024);
    }
    __syncthreads();

    // -- phase 2: sweep (verbatim) --
    f16x8 af[4][4];
#pragma unroll
    for (int s = 0; s < 2; ++s)
#pragma unroll
        for (int m = 0; m < 4; ++m)
            af[s][m] = *reinterpret_cast<const f16x8*>(ztb + lbase[m][s] + ((s & 28) << 6));

    unsigned boff = (unsigned)(w * 4096 + 4 * 262144);
    for (int nt8 = 0; nt8 < 8; ++nt8) {
        const int ntile = nt8 * 8 + w;
        const unsigned wrapAdd = (unsigned)((nt8 < 7 ? 8 : -56) * 4096 - 31 * 262144);
        const int colb = ntile * 64;
        unsigned colw[4];
        float c2[4];
#pragma unroll
        for (int n = 0; n < 4; ++n) {
            colw[n] = (unsigned)(colb + n * 16 + lc);
            c2[n] = cn2p[colw[n]];
        }
        f32x4 acc[4][4];
#pragma unroll
        for (int m = 0; m < 4; ++m)
#pragma unroll
            for (int n = 0; n < 4; ++n)
                acc[m][n] = (f32x4){c2[n], c2[n], c2[n], c2[n]};

#pragma unroll
        for (int kk = 0; kk < 32; ++kk) {
            const int nk2 = (kk + 2) & 31;
#pragma unroll
            for (int m = 0; m < 4; ++m)
                af[(kk + 2) & 3][m] = *reinterpret_cast<const f16x8*>(
                    ztb + lbase[m][nk2 & 3] + ((nk2 & 28) << 6));
            __builtin_amdgcn_s_setprio(1);
#pragma unroll
            for (int m = 0; m < 4; ++m)
#pragma unroll
                for (int n = 0; n < 4; ++n)
                    acc[m][n] = __builtin_amdgcn_mfma_f32_16x16x32_f16(
                        af[kk & 3][m], bf[kk & 3][n], acc[m][n], 0, 0, 0);
            __builtin_amdgcn_s_setprio(0);
#pragma unroll
            for (int n = 0; n < 4; ++n)
                bf[kk & 3][n] = *reinterpret_cast<const f16x8*>(pL + boff + n * 1024);
            boff += (kk == 27) ? wrapAdd : 262144u;
        }

#pragma unroll
        for (int n = 0; n < 4; ++n) {
#pragma unroll
            for (int m = 0; m < 4; ++m)
#pragma unroll
                for (int rg = 0; rg < 4; ++rg) {
                    const unsigned key =
                        (__float_as_uint(acc[m][n][rg]) & 0xFFFFF000u) | colw[n];
                    const int r = m * 4 + rg;
                    const unsigned kmax = umax2(k0[r], key);
                    k0[r] = umin2(k0[r], key);
                    k1[r] = umin2(k1[r], kmax);
                }
        }
    }
#pragma unroll
    for (int off = 1; off < 16; off <<= 1) {
#pragma unroll
        for (int r = 0; r < 16; ++r) {
            const unsigned b0 = __shfl_xor(k0[r], off);
            const unsigned b1 = __shfl_xor(k1[r], off);
            const unsigned lo = umin2(k0[r], b0);
            const unsigned hi = umax2(k0[r], b0);
            k0[r] = lo;
            k1[r] = umin2(hi, umin2(k1[r], b1));
        }
    }

    // -- phase 3: key handoff + refine (verbatim logic) --
    __syncthreads();   // all waves done reading the z panel
    unsigned* pks = (unsigned*)zt;   // [16 slots][64 tokens]
    if (lc == 0) {
#pragma unroll
        for (int m = 0; m < 4; ++m)
#pragma unroll
            for (int rg = 0; rg < 4; ++rg) {
                const int r = m * 4 + rg;
                const int tloc = m * 16 + lg * 4 + rg;
                pks[(w * 2 + 0) * 64 + tloc] = k0[r];
                pks[(w * 2 + 1) * 64 + tloc] = k1[r];
            }
    }
    __syncthreads();

    float asum = 0.0f;
    for (int i = 0; i < 8; ++i) {
        const int tloc = w * 8 + i;
        const int tok = m0 + tloc;
        float4* zp = reinterpret_cast<float4*>(zq + ((size_t)tok << 10));
        float4 zr[4];
#pragma unroll
        for (int j = 0; j < 4; ++j) zr[j] = zp[l + j * 64];

        float zn = 0.0f;
#pragma unroll
        for (int j = 0; j < 4; ++j) {
            zn = fmaf(zr[j].x, zr[j].x, zn);
            zn = fmaf(zr[j].y, zr[j].y, zn);
            zn = fmaf(zr[j].z, zr[j].z, zn);
            zn = fmaf(zr[j].w, zr[j].w, zn);
        }
#pragma unroll
        for (int off = 1; off < 64; off <<= 1) zn += __shfl_xor(zn, off);

        unsigned v = 0xFFFFFFFFu;
        if (l < 16) v = pks[l * 64 + tloc];

        float bestd = 3.4e38f;
        int besti = 0x7fffffff;
#pragma unroll
        for (int s = 0; s < 4; ++s) {
            unsigned mv = v;
#pragma unroll
            for (int off = 1; off < 64; off <<= 1) mv = umin2(mv, __shfl_xor(mv, off));
            if (v == mv) v = 0xFFFFFFFFu;  // consume winner (keys distinct by col)
            const int mi = (int)(mv & 0xFFFu);
            const float4* cp = reinterpret_cast<const float4*>(cb + ((size_t)mi << 10));
            float s4 = 0.0f;
#pragma unroll
            for (int j = 0; j < 4; ++j) {
                const float4 c = cp[l + j * 64];
                s4 = fmaf(zr[j].x, c.x, s4);
                s4 = fmaf(zr[j].y, c.y, s4);
                s4 = fmaf(zr[j].z, c.z, s4);
                s4 = fmaf(zr[j].w, c.w, s4);
            }
#pragma unroll
            for (int off = 1; off < 64; off <<= 1) s4 += __shfl_xor(s4, off);
            const float d = cn2p[mi] - s4;   // shifted by +1024 (rank-invariant)
            if (d < bestd || (d == bestd && mi < besti)) { bestd = d; besti = mi; }
        }
        // quantized = cb[besti] (in place over z; rows owned exclusively)
        const float4* cpb = reinterpret_cast<const float4*>(cb + ((size_t)besti << 10));
#pragma unroll
        for (int j = 0; j < 4; ++j) zp[l + j * 64] = cpb[l + j * 64];

        if (l == 0) {
            idx_f[tok] = (float)besti;
            idxs[tloc] = besti;
            asum += 2.0f * bestd - 2048.0f + zn;
        }
    }
    if (l == 0) atomicAdd(aux, asum * (1.0f / 33554432.0f));

    // -- phase 4: re-stage panel with gathered cbf rows --
    __syncthreads();   // idxs written; all waves done with pks/zq reads
    {
        const int r0 = t >> 7;
        const int ch = t & 127;
#pragma unroll
        for (int i = 0; i < 16; ++i) {
            const int row = i * 4 + r0;
            const int gi = idxs[row];   // static LDS, not clobbered by panel writes
            const int sch = (ch & 0x70) | ((ch ^ row) & 15);
            gload16(cbf + (((size_t)gi) << 10) + sch * 8,
                    zt + ((size_t)(i * 512 + t)) * 8);
        }
    }
    const char* pLo = (const char*)wok + l * 16;
    f16x8 bfo[4][4];
#pragma unroll
    for (int s = 0; s < 4; ++s)
#pragma unroll
        for (int n = 0; n < 4; ++n)
            bfo[s][n] = *reinterpret_cast<const f16x8*>(pLo + s * 32768 + w * 4096 + n * 1024);
    __syncthreads();   // panel staged

    // -- phase 5: outgemm main loop (verbatim; reuses lbase) --
    f16x8 afo[4][4];
#pragma unroll
    for (int s = 0; s < 2; ++s)
#pragma unroll
        for (int m = 0; m < 4; ++m)
            afo[s][m] = *reinterpret_cast<const f16x8*>(ztb + lbase[m][s] + ((s & 28) << 6));

    f32x4 acco[4][4];
#pragma unroll
    for (int n = 0; n < 4; ++n) {
        const float bb = bout[w * 64 + n * 16 + lc];
#pragma unroll
        for (int m = 0; m < 4; ++m)
            acco[m][n] = (f32x4){bb, bb, bb, bb};
    }

    unsigned bo = (unsigned)(w * 4096 + 4 * 32768);
#pragma unroll
    for (int kk = 0; kk < 32; ++kk) {
        const int nk2 = (kk + 2) & 31;
#pragma unroll
        for (int m = 0; m < 4; ++m)
            afo[(kk + 2) & 3][m] = *reinterpret_cast<const f16x8*>(
                ztb + lbase[m][nk2 & 3] + ((nk2 & 28) << 6));
        __builtin_amdgcn_s_setprio(1);
#pragma unroll
        for (int m = 0; m < 4; ++m)
#pragma unroll
            for (int n = 0; n < 4; ++n)
                acco[m][n] = __builtin_amdgcn_mfma_f32_16x16x32_f16(
                    afo[kk & 3][m], bfo[kk & 3][n], acco[m][n], 0, 0, 0);
        __builtin_amdgcn_s_setprio(0);
#pragma unroll
        for (int n = 0; n < 4; ++n)
            bfo[kk & 3][n] = *reinterpret_cast<const f16x8*>(pLo + bo + n * 1024);
        bo += (kk == 27) ? (unsigned)(-(28 * 32768)) : 32768u;
    }

#pragma unroll
    for (int n = 0; n < 4; ++n) {
        const int col = w * 64 + n * 16 + lc;
#pragma unroll
        for (int m = 0; m < 4; ++m)
#pragma unroll
            for (int rg = 0; rg < 4; ++rg) {
                const int row = m0 + m * 16 + lg * 4 + rg;
                out[(size_t)row * DIN + col] = acco[m][n][rg];
            }
    }
}

extern "C" void kernel_launch(void* const* d_in, const int* in_sizes, int n_in,
                              void* d_out, int out_size, void* d_ws, size_t ws_size,
                              hipStream_t stream) {
    const float* x = (const float*)d_in[0];
    const float* w_in = (const float*)d_in[1];
    const float* b_in = (const float*)d_in[2];
    const float* w_out = (const float*)d_in[3];
    const float* b_out = (const float*)d_in[4];
    const float* cb = (const float*)d_in[5];

    float* out = (float*)d_out;              // [32768, 512]
    float* idx_f = out + IDX_OFF;            // [32768] as float
    float* zq = out + Q_OFF;                 // [32768, 1024]: z, then quantized
    float* aux = out + AUX_OFF;              // scalar
    _Float16* zf = (_Float16*)d_out;         // fp16 -z, aliases out slab (64 MiB)

    char* ws = (char*)d_ws;
    float* cn2p = (float*)ws;                          // 16 KB (shifted norms)
    _Float16* cbf = (_Float16*)(ws + 4341760);         // 8 MB flat fp16 codebook
    _Float16* cbp = (_Float16*)(ws + 12730368);        // 8 MB kk-major packed
    _Float16* wpk = (_Float16*)(ws + 21118976);        // 2 MB w_in hi/lo packed
    _Float16* wok = (_Float16*)(ws + 23216128);        // 1 MB w_out packed

    // 1) fused prep: cbf+cn2' | wok | cbp | wpk (all independent ranges)
    prep_all<<<6912, 256, 0, stream>>>(cb, w_out, w_in, cbf, wok, wpk, cbp, cn2p, aux);
    // 2) z = x @ w_in^T + b_in (barrier-free streaming split GEMM)
    zgemm_stream<<<M_TOK / 64, 512, 131072, stream>>>(x, wpk, b_in, zq, zf);
    // 3) mega: distance sweep + exact refine + q gather + out-GEMM
    dist_refine_out<<<M_TOK / 64, 512, 131072, stream>>>(
        zf, cbp, cn2p, cb, cbf, wok, b_out, zq, idx_f, out, aux);
}

// Round 19
// 450.995 us; speedup vs baseline: 1.3795x; 1.0849x over previous
//
#include <hip/hip_runtime.h>

#define M_TOK 32768
#define DIN   512
#define DEMB  1024
#define KC    4096

#define IDX_OFF ((size_t)M_TOK * DIN)                 // 16777216 floats
#define Q_OFF   (IDX_OFF + M_TOK)                     // 16809984
#define AUX_OFF (Q_OFF + (size_t)M_TOK * DEMB)        // 50364416

typedef _Float16 f16x8 __attribute__((ext_vector_type(8)));
typedef _Float16 f16x4 __attribute__((ext_vector_type(4)));
typedef float f32x4 __attribute__((ext_vector_type(4)));

__device__ inline void gload16(const void* g, void* s) {
    __builtin_amdgcn_global_load_lds((const __attribute__((address_space(1))) void*)g,
                                     (__attribute__((address_space(3))) void*)s, 16, 0, 0);
}

__device__ inline unsigned umin2(unsigned a, unsigned b) { return a < b ? a : b; }
__device__ inline unsigned umax2(unsigned a, unsigned b) { return a > b ? a : b; }

// ---------------- block reduction (256 threads = 4 waves) ----------------
__device__ inline float block_reduce_sum_256(float v) {
#pragma unroll
    for (int off = 32; off > 0; off >>= 1) v += __shfl_down(v, off);
    __shared__ float smem[4];
    const int lane = threadIdx.x & 63;
    const int w = threadIdx.x >> 6;
    if (lane == 0) smem[w] = v;
    __syncthreads();
    return smem[0] + smem[1] + smem[2] + smem[3];
}

// ---- fused prep: cbf+cn2' | wok pack | cbp pack | wpk pack --------------
__global__ __launch_bounds__(256) void prep_all(const float* __restrict__ cb,
                                                const float* __restrict__ w_out,
                                                const float* __restrict__ w_in,
                                                _Float16* __restrict__ cbf,
                                                _Float16* __restrict__ wok,
                                                _Float16* __restrict__ wpk,
                                                _Float16* __restrict__ cbp,
                                                float* __restrict__ cn2p,
                                                float* __restrict__ aux) {
    const int b = blockIdx.x;
    if (b < 4096) {
        if (b == 0 && threadIdx.x == 0) *aux = 0.0f;
        const float4 v = reinterpret_cast<const float4*>(cb + (size_t)b * DEMB)[threadIdx.x];
        f16x4 h;
        h[0] = (_Float16)v.x; h[1] = (_Float16)v.y; h[2] = (_Float16)v.z; h[3] = (_Float16)v.w;
        reinterpret_cast<f16x4*>(cbf + (size_t)b * DEMB)[threadIdx.x] = h;
        float s = v.x * v.x + v.y * v.y + v.z * v.z + v.w * v.w;
        s = block_reduce_sum_256(s);
        if (threadIdx.x == 0) cn2p[b] = 0.5f * s + 1024.0f;
    } else if (b < 4352) {
        const int id = (b - 4096) * 256 + threadIdx.x;   // < 65536
        const int l = id & 63;
        const int c16 = (id >> 6) & 31;
        const int kk = id >> 11;                         // 0..31
        const int col = c16 * 16 + (l & 15);
        const int kb = kk * 32 + (l >> 4) * 8;
        const float* src = w_out + (size_t)col * DEMB + kb;
        const float4 a = *reinterpret_cast<const float4*>(src);
        const float4 b4 = *reinterpret_cast<const float4*>(src + 4);
        f16x8 h;
        h[0] = (_Float16)a.x; h[1] = (_Float16)a.y; h[2] = (_Float16)a.z; h[3] = (_Float16)a.w;
        h[4] = (_Float16)b4.x; h[5] = (_Float16)b4.y; h[6] = (_Float16)b4.z; h[7] = (_Float16)b4.w;
        *reinterpret_cast<f16x8*>(wok + (size_t)id * 8) = h;
    } else if (b < 6400) {
        const int id = (b - 4352) * 256 + threadIdx.x;   // < 524288
        const int c16 = id >> 11;                        // 0..255
        const int rem = id & 2047;
        const int kk = rem >> 6;                         // 0..31
        const int l = rem & 63;
        const int lgq = l >> 4, lcq = l & 15;
        const float* src = cb + ((size_t)(c16 * 16 + lcq)) * DEMB + kk * 32 + lgq * 8;
        const float4 a = *reinterpret_cast<const float4*>(src);
        const float4 b4 = *reinterpret_cast<const float4*>(src + 4);
        f16x8 h;
        h[0] = (_Float16)a.x; h[1] = (_Float16)a.y; h[2] = (_Float16)a.z; h[3] = (_Float16)a.w;
        h[4] = (_Float16)b4.x; h[5] = (_Float16)b4.y; h[6] = (_Float16)b4.z; h[7] = (_Float16)b4.w;
        const int ntile = c16 >> 2, nn = c16 & 3;
        const size_t off = ((size_t)(kk * 256 + ntile * 4 + nn)) * 64 + l;   // f16x8 units
        *reinterpret_cast<f16x8*>(cbp + off * 8) = h;
    } else {
        const int id = (b - 6400) * 256 + threadIdx.x;   // < 131072
        const int l = id & 63;
        const int hl = (id >> 6) & 1;                    // wave-uniform
        const int c16 = (id >> 7) & 63;
        const int kk = id >> 13;                         // 0..15
        const int col = c16 * 16 + (l & 15);
        const int kb = kk * 32 + (l >> 4) * 8;
        const float* src = w_in + (size_t)col * DIN + kb;
        const float4 a = *reinterpret_cast<const float4*>(src);
        const float4 b4 = *reinterpret_cast<const float4*>(src + 4);
        const float e[8] = {a.x, a.y, a.z, a.w, b4.x, b4.y, b4.z, b4.w};
        f16x8 o;
#pragma unroll
        for (int j = 0; j < 8; ++j) {
            const _Float16 hv = (_Float16)e[j];
            o[j] = hl ? (_Float16)((e[j] - (float)hv) * 2048.0f) : hv;
        }
        *reinterpret_cast<f16x8*>(wpk + (size_t)id * 8) = o;
    }
}

// ==== single mega kernel: zGEMM + distance sweep + refine + out-GEMM ====
// Phase 0: z = x@w_in^T+b (validated streaming split GEMM), writes zq only.
// Phase 1: stage -z panel by re-reading zq (same-XCD L2-hot; first in-kernel
//          access to those lines was the store -> no stale-L1 hazard).
// Phases 2-5: verbatim R16 (sweep -> keys -> refine+gather -> out-GEMM).
__global__ void __launch_bounds__(512)
__attribute__((amdgpu_waves_per_eu(2, 2)))
vq_fused(const float* __restrict__ x,
         const _Float16* __restrict__ wpk,
         const float* __restrict__ bin,
         const _Float16* __restrict__ cbp,
         const float* __restrict__ cn2p,
         const float* __restrict__ cb,
         const _Float16* __restrict__ cbf,
         const _Float16* __restrict__ wok,
         const float* __restrict__ bout,
         float* __restrict__ zq,
         float* __restrict__ idx_f,
         float* __restrict__ out,
         float* __restrict__ aux) {
    extern __shared__ _Float16 zt[];   // 128 KB: Ah/Al for phase 0, then panel/keys/cbf
    __shared__ int idxs[64];           // static: survives panel overwrite
    const int t = threadIdx.x;
    const int w = t >> 6, l = t & 63;
    const int lg = l >> 4, lc = l & 15;
    const int m0 = blockIdx.x * 64;

    // ---------------- phase 0: z-GEMM (verbatim zgemm_stream, zq only) ----
    {
        _Float16* Ah = zt;             // [64][512] swizzled
        _Float16* Al = zt + 32768;
        {
            const int r = t >> 3;
            const int c0 = t & 7;
#pragma unroll
            for (int i = 0; i < 8; ++i) {
                const int c = c0 + i * 8;
                const float* px = x + (size_t)(m0 + r) * DIN + c * 8;
                const float4 a = *reinterpret_cast<const float4*>(px);
                const float4 b4 = *reinterpret_cast<const float4*>(px + 4);
                const float e[8] = {a.x, a.y, a.z, a.w, b4.x, b4.y, b4.z, b4.w};
                f16x8 h, lo;
#pragma unroll
                for (int j = 0; j < 8; ++j) {
                    const _Float16 hv = (_Float16)e[j];
                    h[j] = hv;
                    lo[j] = (_Float16)((e[j] - (float)hv) * 2048.0f);
                }
                const int swz = (c & 0x30) | ((c ^ r) & 15);
                *reinterpret_cast<f16x8*>(Ah + (size_t)(r * 64 + swz) * 8) = h;
                *reinterpret_cast<f16x8*>(Al + (size_t)(r * 64 + swz) * 8) = lo;
            }
        }
        const char* ztb0 = (const char*)zt;
        int lbase0[4][4];
#pragma unroll
        for (int m = 0; m < 4; ++m)
#pragma unroll
            for (int j = 0; j < 4; ++j)
                lbase0[m][j] = (m * 16 + lc) * 1024 + ((((j * 4) | lg) ^ lc) & 15) * 16;

        const char* pL0 = (const char*)wpk + w * 4096 + l * 16;

        f16x8 bh[2][2], bl[2][2];
#pragma unroll
        for (int s = 0; s < 2; ++s)
#pragma unroll
            for (int n = 0; n < 2; ++n) {
                bh[s][n] = *reinterpret_cast<const f16x8*>(pL0 + s * 131072 + n * 2048);
                bl[s][n] = *reinterpret_cast<const f16x8*>(pL0 + s * 131072 + n * 2048 + 1024);
            }

        __syncthreads();   // x panel staged

        f16x8 ah[2][4], al[2][4];
#pragma unroll
        for (int m = 0; m < 4; ++m) {
            ah[0][m] = *reinterpret_cast<const f16x8*>(ztb0 + lbase0[m][0]);
            al[0][m] = *reinterpret_cast<const f16x8*>(ztb0 + 65536 + lbase0[m][0]);
        }

        unsigned boff = 2u * 131072u;
        for (int p = 0; p < 4; ++p) {
            f32x4 acc1[4][2], acc2[4][2];
#pragma unroll
            for (int n = 0; n < 2; ++n) {
                const float bb = bin[p * 256 + w * 32 + n * 16 + lc];
#pragma unroll
                for (int m = 0; m < 4; ++m) {
                    acc1[m][n] = (f32x4){bb, bb, bb, bb};
                    acc2[m][n] = (f32x4){0.f, 0.f, 0.f, 0.f};
                }
            }
            const unsigned wrapAdd = (unsigned)((p < 3 ? 1 : -3) * 32768 - 15 * 131072);
#pragma unroll
            for (int kk = 0; kk < 16; ++kk) {
                const int nk = (kk + 1) & 15;
#pragma unroll
                for (int m = 0; m < 4; ++m) {
                    ah[(kk + 1) & 1][m] = *reinterpret_cast<const f16x8*>(
                        ztb0 + lbase0[m][nk & 3] + ((nk >> 2) << 8));
                    al[(kk + 1) & 1][m] = *reinterpret_cast<const f16x8*>(
                        ztb0 + 65536 + lbase0[m][nk & 3] + ((nk >> 2) << 8));
                }
                __builtin_amdgcn_s_setprio(1);
#pragma unroll
                for (int m = 0; m < 4; ++m)
#pragma unroll
                    for (int n = 0; n < 2; ++n) {
                        acc1[m][n] = __builtin_amdgcn_mfma_f32_16x16x32_f16(
                            ah[kk & 1][m], bh[kk & 1][n], acc1[m][n], 0, 0, 0);
                        acc2[m][n] = __builtin_amdgcn_mfma_f32_16x16x32_f16(
                            ah[kk & 1][m], bl[kk & 1][n], acc2[m][n], 0, 0, 0);
                        acc2[m][n] = __builtin_amdgcn_mfma_f32_16x16x32_f16(
                            al[kk & 1][m], bh[kk & 1][n], acc2[m][n], 0, 0, 0);
                    }
                __builtin_amdgcn_s_setprio(0);
#pragma unroll
                for (int n = 0; n < 2; ++n) {
                    bh[kk & 1][n] = *reinterpret_cast<const f16x8*>(pL0 + boff + n * 2048);
                    bl[kk & 1][n] = *reinterpret_cast<const f16x8*>(pL0 + boff + n * 2048 + 1024);
                }
                boff += (kk == 13) ? wrapAdd : 131072u;
            }
#pragma unroll
            for (int n = 0; n < 2; ++n) {
                const int col = p * 256 + w * 32 + n * 16 + lc;
#pragma unroll
                for (int m = 0; m < 4; ++m)
#pragma unroll
                    for (int rg = 0; rg < 4; ++rg) {
                        const int row = m0 + m * 16 + lg * 4 + rg;
                        zq[(size_t)row * DEMB + col] =
                            acc1[m][n][rg] + acc2[m][n][rg] * (1.0f / 2048.0f);
                    }
            }
        }
    }

    // ---------------- phase 1: stage -z panel from zq (L2-hot) ------------
    __syncthreads();   // all zq writes drained; x panel dead
    {
        const int r = t >> 3;           // 0..63
        const int c0 = t & 7;
#pragma unroll
        for (int i = 0; i < 16; ++i) {
            const int c = c0 + i * 8;   // chunk 0..127 (8 fp16 each)
            const float* pz = zq + (((size_t)(m0 + r)) << 10) + c * 8;
            const float4 a = *reinterpret_cast<const float4*>(pz);
            const float4 b4 = *reinterpret_cast<const float4*>(pz + 4);
            f16x8 h;
            h[0] = (_Float16)(-a.x);  h[1] = (_Float16)(-a.y);
            h[2] = (_Float16)(-a.z);  h[3] = (_Float16)(-a.w);
            h[4] = (_Float16)(-b4.x); h[5] = (_Float16)(-b4.y);
            h[6] = (_Float16)(-b4.z); h[7] = (_Float16)(-b4.w);
            const int swz = (c & 0x70) | ((c ^ r) & 15);
            *reinterpret_cast<f16x8*>(zt + ((size_t)(r * 128 + swz)) * 8) = h;
        }
    }

    const char* ztb = (const char*)zt;
    int lbase[4][4];
#pragma unroll
    for (int m = 0; m < 4; ++m)
#pragma unroll
        for (int j = 0; j < 4; ++j)
            lbase[m][j] = (m * 16 + lc) * 2048 + ((((j * 4) | lg) ^ lc) << 4);

    unsigned k0[16], k1[16];
#pragma unroll
    for (int r = 0; r < 16; ++r) { k0[r] = 0xFFFFFFFFu; k1[r] = 0xFFFFFFFFu; }

    const char* pL = (const char*)cbp + l * 16;

    f16x8 bf[4][4];
    {
#pragma unroll
        for (int s = 0; s < 4; ++s)
#pragma unroll
            for (int n = 0; n < 4; ++n)
                bf[s][n] = *reinterpret_cast<const f16x8*>(pL + s * 262144 + w * 4096 + n * 1024);
    }
    __syncthreads();   // panel staged

    // ---------------- phase 2: sweep (verbatim) ---------------------------
    f16x8 af[4][4];
#pragma unroll
    for (int s = 0; s < 2; ++s)
#pragma unroll
        for (int m = 0; m < 4; ++m)
            af[s][m] = *reinterpret_cast<const f16x8*>(ztb + lbase[m][s] + ((s & 28) << 6));

    unsigned boff = (unsigned)(w * 4096 + 4 * 262144);
    for (int nt8 = 0; nt8 < 8; ++nt8) {
        const int ntile = nt8 * 8 + w;
        const unsigned wrapAdd = (unsigned)((nt8 < 7 ? 8 : -56) * 4096 - 31 * 262144);
        const int colb = ntile * 64;
        unsigned colw[4];
        float c2[4];
#pragma unroll
        for (int n = 0; n < 4; ++n) {
            colw[n] = (unsigned)(colb + n * 16 + lc);
            c2[n] = cn2p[colw[n]];
        }
        f32x4 acc[4][4];
#pragma unroll
        for (int m = 0; m < 4; ++m)
#pragma unroll
            for (int n = 0; n < 4; ++n)
                acc[m][n] = (f32x4){c2[n], c2[n], c2[n], c2[n]};

#pragma unroll
        for (int kk = 0; kk < 32; ++kk) {
            const int nk2 = (kk + 2) & 31;
#pragma unroll
            for (int m = 0; m < 4; ++m)
                af[(kk + 2) & 3][m] = *reinterpret_cast<const f16x8*>(
                    ztb + lbase[m][nk2 & 3] + ((nk2 & 28) << 6));
            __builtin_amdgcn_s_setprio(1);
#pragma unroll
            for (int m = 0; m < 4; ++m)
#pragma unroll
                for (int n = 0; n < 4; ++n)
                    acc[m][n] = __builtin_amdgcn_mfma_f32_16x16x32_f16(
                        af[kk & 3][m], bf[kk & 3][n], acc[m][n], 0, 0, 0);
            __builtin_amdgcn_s_setprio(0);
#pragma unroll
            for (int n = 0; n < 4; ++n)
                bf[kk & 3][n] = *reinterpret_cast<const f16x8*>(pL + boff + n * 1024);
            boff += (kk == 27) ? wrapAdd : 262144u;
        }

#pragma unroll
        for (int n = 0; n < 4; ++n) {
#pragma unroll
            for (int m = 0; m < 4; ++m)
#pragma unroll
                for (int rg = 0; rg < 4; ++rg) {
                    const unsigned key =
                        (__float_as_uint(acc[m][n][rg]) & 0xFFFFF000u) | colw[n];
                    const int r = m * 4 + rg;
                    const unsigned kmax = umax2(k0[r], key);
                    k0[r] = umin2(k0[r], key);
                    k1[r] = umin2(k1[r], kmax);
                }
        }
    }
#pragma unroll
    for (int off = 1; off < 16; off <<= 1) {
#pragma unroll
        for (int r = 0; r < 16; ++r) {
            const unsigned b0 = __shfl_xor(k0[r], off);
            const unsigned b1 = __shfl_xor(k1[r], off);
            const unsigned lo = umin2(k0[r], b0);
            const unsigned hi = umax2(k0[r], b0);
            k0[r] = lo;
            k1[r] = umin2(hi, umin2(k1[r], b1));
        }
    }

    // ---------------- phase 3: key handoff + refine (verbatim) ------------
    __syncthreads();   // all waves done reading the z panel
    unsigned* pks = (unsigned*)zt;   // [16 slots][64 tokens]
    if (lc == 0) {
#pragma unroll
        for (int m = 0; m < 4; ++m)
#pragma unroll
            for (int rg = 0; rg < 4; ++rg) {
                const int r = m * 4 + rg;
                const int tloc = m * 16 + lg * 4 + rg;
                pks[(w * 2 + 0) * 64 + tloc] = k0[r];
                pks[(w * 2 + 1) * 64 + tloc] = k1[r];
            }
    }
    __syncthreads();

    float asum = 0.0f;
    for (int i = 0; i < 8; ++i) {
        const int tloc = w * 8 + i;
        const int tok = m0 + tloc;
        float4* zp = reinterpret_cast<float4*>(zq + ((size_t)tok << 10));
        float4 zr[4];
#pragma unroll
        for (int j = 0; j < 4; ++j) zr[j] = zp[l + j * 64];

        float zn = 0.0f;
#pragma unroll
        for (int j = 0; j < 4; ++j) {
            zn = fmaf(zr[j].x, zr[j].x, zn);
            zn = fmaf(zr[j].y, zr[j].y, zn);
            zn = fmaf(zr[j].z, zr[j].z, zn);
            zn = fmaf(zr[j].w, zr[j].w, zn);
        }
#pragma unroll
        for (int off = 1; off < 64; off <<= 1) zn += __shfl_xor(zn, off);

        unsigned v = 0xFFFFFFFFu;
        if (l < 16) v = pks[l * 64 + tloc];

        float bestd = 3.4e38f;
        int besti = 0x7fffffff;
#pragma unroll
        for (int s = 0; s < 4; ++s) {
            unsigned mv = v;
#pragma unroll
            for (int off = 1; off < 64; off <<= 1) mv = umin2(mv, __shfl_xor(mv, off));
            if (v == mv) v = 0xFFFFFFFFu;  // consume winner (keys distinct by col)
            const int mi = (int)(mv & 0xFFFu);
            const float4* cp = reinterpret_cast<const float4*>(cb + ((size_t)mi << 10));
            float s4 = 0.0f;
#pragma unroll
            for (int j = 0; j < 4; ++j) {
                const float4 c = cp[l + j * 64];
                s4 = fmaf(zr[j].x, c.x, s4);
                s4 = fmaf(zr[j].y, c.y, s4);
                s4 = fmaf(zr[j].z, c.z, s4);
                s4 = fmaf(zr[j].w, c.w, s4);
            }
#pragma unroll
            for (int off = 1; off < 64; off <<= 1) s4 += __shfl_xor(s4, off);
            const float d = cn2p[mi] - s4;   // shifted by +1024 (rank-invariant)
            if (d < bestd || (d == bestd && mi < besti)) { bestd = d; besti = mi; }
        }
        const float4* cpb = reinterpret_cast<const float4*>(cb + ((size_t)besti << 10));
#pragma unroll
        for (int j = 0; j < 4; ++j) zp[l + j * 64] = cpb[l + j * 64];

        if (l == 0) {
            idx_f[tok] = (float)besti;
            idxs[tloc] = besti;
            asum += 2.0f * bestd - 2048.0f + zn;
        }
    }
    if (l == 0) atomicAdd(aux, asum * (1.0f / 33554432.0f));

    // ---------------- phase 4: re-stage panel with gathered cbf rows ------
    __syncthreads();   // idxs written; all waves done with pks/zq reads
    {
        const int r0 = t >> 7;
        const int ch = t & 127;
#pragma unroll
        for (int i = 0; i < 16; ++i) {
            const int row = i * 4 + r0;
            const int gi = idxs[row];
            const int sch = (ch & 0x70) | ((ch ^ row) & 15);
            gload16(cbf + (((size_t)gi) << 10) + sch * 8,
                    zt + ((size_t)(i * 512 + t)) * 8);
        }
    }
    const char* pLo = (const char*)wok + l * 16;
    f16x8 bfo[4][4];
#pragma unroll
    for (int s = 0; s < 4; ++s)
#pragma unroll
        for (int n = 0; n < 4; ++n)
            bfo[s][n] = *reinterpret_cast<const f16x8*>(pLo + s * 32768 + w * 4096 + n * 1024);
    __syncthreads();   // panel staged

    // ---------------- phase 5: out-GEMM (verbatim; reuses lbase) ----------
    f16x8 afo[4][4];
#pragma unroll
    for (int s = 0; s < 2; ++s)
#pragma unroll
        for (int m = 0; m < 4; ++m)
            afo[s][m] = *reinterpret_cast<const f16x8*>(ztb + lbase[m][s] + ((s & 28) << 6));

    f32x4 acco[4][4];
#pragma unroll
    for (int n = 0; n < 4; ++n) {
        const float bb = bout[w * 64 + n * 16 + lc];
#pragma unroll
        for (int m = 0; m < 4; ++m)
            acco[m][n] = (f32x4){bb, bb, bb, bb};
    }

    unsigned bo = (unsigned)(w * 4096 + 4 * 32768);
#pragma unroll
    for (int kk = 0; kk < 32; ++kk) {
        const int nk2 = (kk + 2) & 31;
#pragma unroll
        for (int m = 0; m < 4; ++m)
            afo[(kk + 2) & 3][m] = *reinterpret_cast<const f16x8*>(
                ztb + lbase[m][nk2 & 3] + ((nk2 & 28) << 6));
        __builtin_amdgcn_s_setprio(1);
#pragma unroll
        for (int m = 0; m < 4; ++m)
#pragma unroll
            for (int n = 0; n < 4; ++n)
                acco[m][n] = __builtin_amdgcn_mfma_f32_16x16x32_f16(
                    afo[kk & 3][m], bfo[kk & 3][n], acco[m][n], 0, 0, 0);
        __builtin_amdgcn_s_setprio(0);
#pragma unroll
        for (int n = 0; n < 4; ++n)
            bfo[kk & 3][n] = *reinterpret_cast<const f16x8*>(pLo + bo + n * 1024);
        bo += (kk == 27) ? (unsigned)(-(28 * 32768)) : 32768u;
    }

#pragma unroll
    for (int n = 0; n < 4; ++n) {
        const int col = w * 64 + n * 16 + lc;
#pragma unroll
        for (int m = 0; m < 4; ++m)
#pragma unroll
            for (int rg = 0; rg < 4; ++rg) {
                const int row = m0 + m * 16 + lg * 4 + rg;
                out[(size_t)row * DIN + col] = acco[m][n][rg];
            }
    }
}

extern "C" void kernel_launch(void* const* d_in, const int* in_sizes, int n_in,
                              void* d_out, int out_size, void* d_ws, size_t ws_size,
                              hipStream_t stream) {
    const float* x = (const float*)d_in[0];
    const float* w_in = (const float*)d_in[1];
    const float* b_in = (const float*)d_in[2];
    const float* w_out = (const float*)d_in[3];
    const float* b_out = (const float*)d_in[4];
    const float* cb = (const float*)d_in[5];

    float* out = (float*)d_out;              // [32768, 512]
    float* idx_f = out + IDX_OFF;            // [32768] as float
    float* zq = out + Q_OFF;                 // [32768, 1024]: z, then quantized
    float* aux = out + AUX_OFF;              // scalar

    char* ws = (char*)d_ws;
    float* cn2p = (float*)ws;                          // 16 KB (shifted norms)
    _Float16* cbf = (_Float16*)(ws + 4341760);         // 8 MB flat fp16 codebook
    _Float16* cbp = (_Float16*)(ws + 12730368);        // 8 MB kk-major packed
    _Float16* wpk = (_Float16*)(ws + 21118976);        // 2 MB w_in hi/lo packed
    _Float16* wok = (_Float16*)(ws + 23216128);        // 1 MB w_out packed

    // 1) fused prep: cbf+cn2' | wok | cbp | wpk (all independent ranges)
    prep_all<<<6912, 256, 0, stream>>>(cb, w_out, w_in, cbf, wok, wpk, cbp, cn2p, aux);
    // 2) single mega kernel: zGEMM + sweep + refine + gather + outGEMM
    vq_fused<<<M_TOK / 64, 512, 131072, stream>>>(
        x, wpk, b_in, cbp, cn2p, cb, cbf, wok, b_out, zq, idx_f, out, aux);
}